// Round 4
// baseline (1035.799 us; speedup 1.0000x reference)
//
#include <hip/hip_runtime.h>

// VectorQuantizer: x [32768, 256] fp32, codebook [1024, 256] fp32.
// Reference (recomputed by harness in float32):
//   d[n,k] = fl( fl( ||x_n||^2 - 2*dot(x_n,c_k) ) + ||c_k||^2 )   (all fp32)
//   idx = argmin_k (first min), out = codebook[idx]
// We REPLICATE the fp32 arithmetic exactly:
//  - dot: single sequential fp32 FMA chain over d ascending (v_fmac_f32, no
//    reassociation at -O3). LDS round-trip of x is a bit-exact fp32 copy.
//  - q = (S - 2*acc) + cn in fp32: two roundings (2*acc exact), left-to-right.
//  - S/cnorm: fp64 butterfly sums rounded once to fp32 (unchanged kernel).
//  - ties: per-lane scan is ascending k with strict <; cross-wave merge
//    tie-breaks on smaller index  -> np.argmin first-hit.
//
// R3 post-mortem: sreg[8] held across the FMA loop + barrier spilled EVERY
// chunk (WRITE_SIZE exactly 512 MB = 512 thr*128B*16 chunks*512 blocks,
// VGPR collapsed to 52); spill traffic thrashed L2 so scalar x re-reads came
// from HBM (FETCH 781 MB). Lesson (3rd time): nothing register-resident
// across barriers/long regions. Free finding: per-lane ds_read_b128 at
// stride 260 floats measured SQ_LDS_BANK_CONFLICT = 0.
//
// R4: x-tile in LDS staged ONCE (no main-loop barriers, nothing to spill).
// Lane l owns x-row n0+l (1 conflict-free ds_read_b128 per 4-d group).
// Wave w owns k in [128w, 128w+128), 8 k's at a time: codebook rows stream
// as wave-uniform global_load_dwordx4 (raw tid>>6 addressing forces the
// vector path; HW coalesces equal addresses to one line). cb is 1 MB,
// L2-resident across all 512 blocks. LDS-pipe ratio 16w*12cy/(4*256cy)=0.75.
// vm (cb) and lgkm (ds) counters independent -> compiler pipelines cleanly.

#define D         256
#define K_TOTAL   1024
#define N_ROWS    32768
#define TM        64            // x-rows per block = 64 lanes
#define NTHREADS  512
#define WAVES     8
#define KPW       (K_TOTAL / WAVES)   // 128 k per wave, contiguous
#define KG        8             // k's processed together (acc chains)
#define CSTR      260           // xs row stride floats (1040 B = 65*16 B, conflict-free)

// ---------------- kernel 1: row norms for x and codebook ----------------
// Unchanged (bit-exact): fp32 squares -> fp64 left-assoc sum of 4 ->
// shfl_down butterfly 32..1 -> single fp64->fp32 rounding.
__global__ void norms_kernel(const float* __restrict__ x, const float* __restrict__ cb,
                             float* __restrict__ xnorm, float* __restrict__ cnorm) {
    const int wave = threadIdx.x >> 6;          // 0..3
    const int lane = threadIdx.x & 63;
    const int row0 = (blockIdx.x * 4 + wave) * 4;   // 4 rows per wave

    double s[4];
    #pragma unroll
    for (int r = 0; r < 4; ++r) {
        const int row = row0 + r;
        const float* src = (row < N_ROWS) ? (x + (size_t)row * D)
                                          : (cb + (size_t)(row - N_ROWS) * D);
        float4 v = *(const float4*)(src + lane * 4);
        float sx = v.x * v.x;
        float sy = v.y * v.y;
        float sz = v.z * v.z;
        float sw = v.w * v.w;
        s[r] = (double)sx + (double)sy + (double)sz + (double)sw;
    }
    #pragma unroll
    for (int off = 32; off > 0; off >>= 1) {
        #pragma unroll
        for (int r = 0; r < 4; ++r) s[r] += __shfl_down(s[r], off, 64);
    }
    if (lane == 0) {
        #pragma unroll
        for (int r = 0; r < 4; ++r) {
            const int row = row0 + r;
            if (row < N_ROWS) xnorm[row] = (float)s[r];
            else              cnorm[row - N_ROWS] = (float)s[r];
        }
    }
}

// ---------------- kernel 2: x-in-LDS, uniform-streamed codebook ----------------
__global__ __launch_bounds__(NTHREADS, 4)
void vq_kernel(const float* __restrict__ x, const float* __restrict__ cb,
               const float* __restrict__ xnorm, const float* __restrict__ cnorm,
               float* __restrict__ out) {
    __shared__ float xs[TM * CSTR];          // 66560 B x tile [64 n][256 d]
    __shared__ float red_val[TM * WAVES];    // 2048 B
    __shared__ int   red_idx[TM * WAVES];    // 2048 B
    __shared__ int   best[TM];               // 256 B  -> ~71 KB, 2 blocks/CU

    const int tid  = threadIdx.x;
    const int lane = tid & 63;
    const int w    = tid >> 6;               // raw (not readfirstlane): keeps cb
                                             // addressing on the VECTOR load path
    const int n0   = blockIdx.x * TM;

    // staging geometry: 64 rows x 8 float4-cols x 8 iters per 512 threads
    const int trow = tid >> 3;               // 0..63
    const int tc4  = tid & 7;                // 0..7

    // ---- stage x tile ONCE (coalesced 16B) ----
    {
        const float* src = x + (size_t)(n0 + trow) * D + tc4 * 4;
        float* dst = xs + trow * CSTR + tc4 * 4;
        #pragma unroll
        for (int j = 0; j < 8; ++j) {
            float4 v = *(const float4*)(src + 32 * j);
            *(float4*)(dst + 32 * j) = v;
        }
    }
    __syncthreads();                         // the ONLY barrier before the merge

    const float  Sv   = xnorm[n0 + lane];    // per-lane row norm
    const float* xrow = xs + lane * CSTR;    // conflict-free per-lane row base

    float runmin = 1e30f;
    int   runidx = 0;

    const int kb0 = w * KPW;                 // this wave's contiguous k range

    for (int t = 0; t < KPW / KG; ++t) {     // 16 k-groups of 8
        const int kbase = kb0 + t * KG;
        const float* cbp = cb + (size_t)kbase * D;

        // cnorms for the group: two uniform 16B loads
        const float4 cn0 = *(const float4*)(cnorm + kbase);
        const float4 cn1 = *(const float4*)(cnorm + kbase + 4);

        float acc[KG];
        #pragma unroll
        for (int j = 0; j < KG; ++j) acc[j] = 0.f;

        // ---- d-loop: 1 ds_read_b128 + 8 uniform global 16B loads + 32 FMA
        // per 4-d group. Sequential fp32 chain per (row,k), d ascending —
        // DO NOT reorder. ----
        #pragma unroll 2
        for (int dd = 0; dd < D; dd += 4) {
            const float4 xv = *(const float4*)(xrow + dd);
            #pragma unroll
            for (int j = 0; j < KG; ++j) {
                const float4 bv = *(const float4*)(cbp + j * D + dd);
                acc[j] += xv.x * bv.x;
                acc[j] += xv.y * bv.y;
                acc[j] += xv.z * bv.z;
                acc[j] += xv.w * bv.w;
            }
        }

        // np-replica fp32 distance: q = (S - 2*acc) + cn, two roundings.
        const float cna[KG] = {cn0.x, cn0.y, cn0.z, cn0.w,
                               cn1.x, cn1.y, cn1.z, cn1.w};
        #pragma unroll
        for (int j = 0; j < KG; ++j) {
            const float tt = Sv - 2.0f * acc[j];   // one rounding (2*acc exact)
            const float q  = tt + cna[j];          // second rounding
            if (q < runmin) { runmin = q; runidx = kbase + j; }
        }
    }

    // ---- merge the 8 per-wave candidates for each row ----
    red_val[lane * WAVES + w] = runmin;
    red_idx[lane * WAVES + w] = runidx;
    __syncthreads();
    if (tid < TM) {
        const int row = tid;
        float bv = red_val[row * WAVES];
        int   bi = red_idx[row * WAVES];
        #pragma unroll
        for (int u = 1; u < WAVES; ++u) {
            const float v = red_val[row * WAVES + u];
            const int  ix = red_idx[row * WAVES + u];
            if (v < bv || (v == bv && ix < bi)) { bv = v; bi = ix; }
        }
        best[row] = bi;
    }
    __syncthreads();

    // ---- gather winning codebook rows -> out, 16B coalesced ----
    {
        const int krow = best[trow];
        const float* src = cb + (size_t)krow * D + tc4 * 4;
        float* dst = out + (size_t)(n0 + trow) * D + tc4 * 4;
        #pragma unroll
        for (int j = 0; j < 8; ++j) {
            float4 v = *(const float4*)(src + 32 * j);
            *(float4*)(dst + 32 * j) = v;
        }
    }
}

extern "C" void kernel_launch(void* const* d_in, const int* in_sizes, int n_in,
                              void* d_out, int out_size, void* d_ws, size_t ws_size,
                              hipStream_t stream) {
    const float* x  = (const float*)d_in[0];   // [32768, 256]
    const float* cb = (const float*)d_in[1];   // [1024, 256]
    float* out = (float*)d_out;                // [32768, 256]

    // workspace: xnorm [32768 fp32] | cnorm [1024 fp32]  (132 KB)
    float* xnorm = (float*)d_ws;
    float* cnorm = xnorm + N_ROWS;

    norms_kernel<<<(N_ROWS + K_TOTAL) / 16, 256, 0, stream>>>(x, cb, xnorm, cnorm);
    vq_kernel<<<N_ROWS / TM, NTHREADS, 0, stream>>>(x, cb, xnorm, cnorm, out);
}

// Round 5
// 496.864 us; speedup vs baseline: 2.0847x; 2.0847x over previous
//
#include <hip/hip_runtime.h>

// VectorQuantizer: x [32768, 256] fp32, codebook [1024, 256] fp32.
// Reference (recomputed by harness in float32):
//   d[n,k] = fl( fl( ||x_n||^2 - 2*dot(x_n,c_k) ) + ||c_k||^2 )   (all fp32)
//   idx = argmin_k (first min), out = codebook[idx]
// fp32-replica rules (unchanged since R0):
//  - dot: single sequential fp32 FMA chain over d ascending per (n,k).
//  - q = (S - 2*acc) + cn: two fp32 roundings, left-to-right.
//  - S/cnorm: fp64 butterfly sums rounded once to fp32 (norms kernel as R0).
//  - ties -> smallest k (strict <, ascending k; merges tie-break on index).
//
// Round ledger:
//  R1/R2/R3: register prefetch arrays across barriers ALWAYS spill (250-500MB
//    scratch traffic). Banned pattern.
//  R4: zero spills but 16 unhidden L2-latency loads per 64 FMA-instrs at
//    2 waves/SIMD -> 9.5x floor. Exposed latency is the enemy.
//  Model: time ~ max(pipe, latency x load-groups); lever = register tile:
//    loads/FMA-instr = (NI+NJ)/(4*NI*NJ).
// R5: NI=8 x NJ=4 tile (2.7x fewer loads/FMA than R0's 4x4), synchronous
//  staging, nothing register-resident across barriers. a-loads: 8 consecutive
//  rows/thread -> 4 distinct addrs/wave (near-scalar cost, L1/L2). b-loads:
//  4 ds_read_b128, start-bank 4*tx%32 -> 2-way = free. 128 FMA-instrs per
//  load group = 64 issue-cy windows for the compiler to hide latency in.

#define D         256
#define K_TOTAL   1024
#define N_ROWS    32768
#define TM        128           // rows per block -> grid 256 = 1 block/CU
#define TN        64            // k per staged chunk
#define NCHUNK    (K_TOTAL / TN)
#define NTHREADS  256
#define NI        8             // rows per thread (consecutive)
#define NJ        4             // ks per thread (k = k0 + tx + 16*j)
#define CSTR      260           // cs row stride floats (1040 B): reads 2-way bank = free

// ---------------- kernel 1: row norms for x and codebook ----------------
// Unchanged (bit-exact): fp32 squares -> fp64 left-assoc sum of 4 ->
// shfl_down butterfly 32..1 -> single fp64->fp32 rounding.
__global__ void norms_kernel(const float* __restrict__ x, const float* __restrict__ cb,
                             float* __restrict__ xnorm, float* __restrict__ cnorm) {
    const int wave = threadIdx.x >> 6;          // 0..3
    const int lane = threadIdx.x & 63;
    const int row0 = (blockIdx.x * 4 + wave) * 4;   // 4 rows per wave

    double s[4];
    #pragma unroll
    for (int r = 0; r < 4; ++r) {
        const int row = row0 + r;
        const float* src = (row < N_ROWS) ? (x + (size_t)row * D)
                                          : (cb + (size_t)(row - N_ROWS) * D);
        float4 v = *(const float4*)(src + lane * 4);
        float sx = v.x * v.x;
        float sy = v.y * v.y;
        float sz = v.z * v.z;
        float sw = v.w * v.w;
        s[r] = (double)sx + (double)sy + (double)sz + (double)sw;
    }
    #pragma unroll
    for (int off = 32; off > 0; off >>= 1) {
        #pragma unroll
        for (int r = 0; r < 4; ++r) s[r] += __shfl_down(s[r], off, 64);
    }
    if (lane == 0) {
        #pragma unroll
        for (int r = 0; r < 4; ++r) {
            const int row = row0 + r;
            if (row < N_ROWS) xnorm[row] = (float)s[r];
            else              cnorm[row - N_ROWS] = (float)s[r];
        }
    }
}

// ---------------- kernel 2: 8x4 register-tile distance + argmin + gather ----------------
__global__ __launch_bounds__(NTHREADS, 1)   // min-waves 1: no allocator occupancy squeeze
void vq_kernel(const float* __restrict__ x, const float* __restrict__ cb,
               const float* __restrict__ xnorm, const float* __restrict__ cnorm,
               float* __restrict__ out) {
    __shared__ float cs[TN * CSTR];          // 66560 B codebook chunk
    __shared__ int   best[TM];               // 512 B

    const int tid = threadIdx.x;
    const int tx  = tid & 15;                // k owner
    const int ty  = tid >> 4;                // row-group owner, 0..15
    const int n0  = blockIdx.x * TM;

    // thread's 8 consecutive x rows: wave has only 4 distinct ty -> a-load
    // instructions present 4 distinct addresses (TA-cheap, broadcast-like)
    const float* xbase = x + (size_t)(n0 + ty * NI) * D;

    float S[NI];
    #pragma unroll
    for (int r = 0; r < NI; ++r) S[r] = xnorm[n0 + ty * NI + r];

    float runmin[NI];
    int   runidx[NI];
    #pragma unroll
    for (int r = 0; r < NI; ++r) { runmin[r] = 1e30f; runidx[r] = 0; }

    // staging geometry: per wave, trow = lane&15 (16 rows), colseg = lane>>4.
    // ds_write start-bank = 4*trow % 32 -> 2-way = free. Each thread loads a
    // CONTIGUOUS 256 B of its cb row (L1-friendly).
    const int trow   = (tid & 15) + ((tid >> 6) << 4);   // 0..63 across 4 waves
    const int colseg = (tid >> 4) & 3;                   // 0..3

    for (int kc = 0; kc < NCHUNK; ++kc) {
        const int k0 = kc * TN;

        __syncthreads();                     // protect cs from previous readers
        {   // synchronous stage: 64 rows x 64 float4; 16 float4 per thread
            const float* src = cb + (size_t)(k0 + trow) * D + colseg * 64;
            float* dst = cs + trow * CSTR + colseg * 64;
            #pragma unroll
            for (int jj = 0; jj < 16; ++jj) {
                float4 v = *(const float4*)(src + jj * 4);
                *(float4*)(dst + jj * 4) = v;
            }
        }
        __syncthreads();

        float cn[NJ];
        #pragma unroll
        for (int j = 0; j < NJ; ++j) cn[j] = cnorm[k0 + tx + 16 * j];

        float acc[NI][NJ];
        #pragma unroll
        for (int r = 0; r < NI; ++r)
            #pragma unroll
            for (int j = 0; j < NJ; ++j) acc[r][j] = 0.f;

        // ---- d-loop: 8 global a-loads + 4 free ds_read_b128 per 128
        // FMA-instrs. Sequential fp32 chain per (row,k), d ascending —
        // DO NOT reorder accumulation within a chain. ----
        #pragma unroll 2
        for (int dd = 0; dd < D; dd += 4) {
            float4 b[NJ];
            #pragma unroll
            for (int j = 0; j < NJ; ++j)
                b[j] = *(const float4*)(cs + (tx + 16 * j) * CSTR + dd);
            float4 a[NI];
            #pragma unroll
            for (int r = 0; r < NI; ++r)
                a[r] = *(const float4*)(xbase + r * D + dd);
            #pragma unroll
            for (int r = 0; r < NI; ++r)
                #pragma unroll
                for (int j = 0; j < NJ; ++j) {
                    acc[r][j] += a[r].x * b[j].x;
                    acc[r][j] += a[r].y * b[j].y;
                    acc[r][j] += a[r].z * b[j].z;
                    acc[r][j] += a[r].w * b[j].w;
                }
        }

        // np-replica fp32 distance: q = (S - 2*acc) + cn, two roundings.
        #pragma unroll
        for (int j = 0; j < NJ; ++j) {
            const int k = k0 + tx + 16 * j;
            #pragma unroll
            for (int r = 0; r < NI; ++r) {
                const float t = S[r] - 2.0f * acc[r][j];   // one rounding (2*acc exact)
                const float q = t + cn[j];                 // second rounding
                if (q < runmin[r]) { runmin[r] = q; runidx[r] = k; }
            }
        }
    }

    // ---- merge 16 tx-candidates per row: the 16 owners of a row are 16
    // CONTIGUOUS lanes of one wave -> shfl_down tree, index tie-break ----
    #pragma unroll
    for (int r = 0; r < NI; ++r) {
        float v = runmin[r];
        int  ix = runidx[r];
        #pragma unroll
        for (int off = 8; off > 0; off >>= 1) {
            const float ov = __shfl_down(v, off, 64);
            const int   oi = __shfl_down(ix, off, 64);
            if (ov < v || (ov == v && oi < ix)) { v = ov; ix = oi; }
        }
        if (tx == 0) best[ty * NI + r] = ix;
    }
    __syncthreads();

    // ---- gather winning codebook rows -> out, coalesced ----
    // 128 rows x 64 float4 / 256 threads = 32 float4 each.
    {
        const int grow = tid >> 4;           // 0..15
        const int gcol = tid & 15;           // 0..15
        #pragma unroll
        for (int rr = 0; rr < 8; ++rr) {
            const int row = grow + 16 * rr;
            const int k   = best[row];
            const float* src = cb + (size_t)k * D + gcol * 4;
            float* dst = out + (size_t)(n0 + row) * D + gcol * 4;
            #pragma unroll
            for (int cc = 0; cc < 4; ++cc) {
                float4 v = *(const float4*)(src + cc * 64);
                *(float4*)(dst + cc * 64) = v;
            }
        }
    }
}

extern "C" void kernel_launch(void* const* d_in, const int* in_sizes, int n_in,
                              void* d_out, int out_size, void* d_ws, size_t ws_size,
                              hipStream_t stream) {
    const float* x  = (const float*)d_in[0];   // [32768, 256]
    const float* cb = (const float*)d_in[1];   // [1024, 256]
    float* out = (float*)d_out;                // [32768, 256]

    // workspace: xnorm [32768 fp32] | cnorm [1024 fp32]  (132 KB)
    float* xnorm = (float*)d_ws;
    float* cnorm = xnorm + N_ROWS;

    norms_kernel<<<(N_ROWS + K_TOTAL) / 16, 256, 0, stream>>>(x, cb, xnorm, cnorm);
    vq_kernel<<<N_ROWS / TM, NTHREADS, 0, stream>>>(x, cb, xnorm, cnorm, out);
}